// Round 1
// baseline (143.973 us; speedup 1.0000x reference)
//
#include <hip/hip_runtime.h>

#define BB 4
#define T_IN 12
#define T_OUT 24
#define NNODE 20000
#define CC 16
#define KP1 9
#define NH 8
#define JJ 12  // T_OUT - T_IN

// out[:, :12] = x  (straight float4 copy)
__global__ __launch_bounds__(256) void copy_x_kernel(const float4* __restrict__ x,
                                                     float4* __restrict__ out) {
    const int per_b = T_IN * NNODE * (CC / 4);
    const int total = BB * per_b;
    const int out_per_b = T_OUT * NNODE * (CC / 4);
    for (int i = blockIdx.x * blockDim.x + threadIdx.x; i < total;
         i += gridDim.x * blockDim.x) {
        int b = i / per_b;
        int rem = i - b * per_b;
        out[b * out_per_b + rem] = x[i];
    }
}

// One thread per (b, n, c). Block = 16 nodes x 16 channels.
__global__ __launch_bounds__(256) void gal_main(
    const float* __restrict__ x,         // (B,12,N,16)
    const int* __restrict__ nn,          // (N,9)
    const float* __restrict__ agg_w,     // (1,9)
    const float* __restrict__ agg_b,     // (1,)
    const float* __restrict__ mh_w,      // (8,1)
    const float* __restrict__ mh_b,      // (8,)
    const float* __restrict__ shrink_w,  // (12,96)
    const float* __restrict__ shrink_b,  // (12,)
    float* __restrict__ out)             // (B,24,N,16)
{
    __shared__ float sWc[JJ][T_IN];   // collapsed weight: Wc[j][t] = sum_h mh_w[h]*W[j,t*8+h]
    __shared__ float sBc[JJ];         // collapsed bias
    __shared__ float sAggW[KP1];
    __shared__ float sAggB;
    __shared__ int   sNN[16][KP1];

    const int tid = threadIdx.x;
    const int row0 = blockIdx.x * 16;        // global (b*N + n) base for this block
    const int b = row0 / NNODE;              // N % 16 == 0, so b is uniform per block
    const int n0 = row0 - b * NNODE;

    // --- per-block tiny precompute (redundant across blocks; negligible) ---
    if (tid < JJ * T_IN) {
        int j = tid / T_IN, t = tid - j * T_IN;
        float s = 0.f;
#pragma unroll
        for (int h = 0; h < NH; ++h)
            s += mh_w[h] * shrink_w[j * (T_IN * NH) + t * NH + h];
        sWc[j][t] = s;
    }
    if (tid < JJ) {
        float s = shrink_b[tid];
#pragma unroll
        for (int q = 0; q < T_IN * NH; ++q)
            s += mh_b[q & (NH - 1)] * shrink_w[tid * (T_IN * NH) + q];
        sBc[tid] = s;
    }
    if (tid < KP1) sAggW[tid] = agg_w[tid];
    if (tid == 0) sAggB = agg_b[0];
    if (tid < 16 * KP1) {
        int r = tid / KP1, k = tid - r * KP1;
        sNN[r][k] = nn[(n0 + r) * KP1 + k];
    }
    __syncthreads();

    const int r = tid >> 4;        // local node 0..15
    const int c = tid & 15;        // channel 0..15
    const int n = n0 + r;

    // --- gather + aggregate + swish, per t ---
    float a[T_IN];
    const float* xb = x + (size_t)b * (T_IN * NNODE * CC) + c;
#pragma unroll
    for (int t = 0; t < T_IN; ++t) {
        float s = sAggB;
        const float* xt = xb + t * (NNODE * CC);
#pragma unroll
        for (int k = 0; k < KP1; ++k) {
            int idx = sNN[r][k];
            float w = sAggW[k];
            if (idx >= NNODE) { idx = 0; w = 0.f; }   // padded zero-node
            s += w * xt[idx * CC];
        }
        // swish: s * sigmoid(0.8*s)
        a[t] = s / (1.f + __expf(-0.8f * s));
    }

    // --- EMA over t (in place, back-to-front) ---
#pragma unroll
    for (int t = T_IN - 1; t >= 1; --t) a[t] = 0.8f * a[t] + 0.2f * a[t - 1];

    // --- 12x12 collapsed matmul + selu + store ---
    float* ob = out + ((size_t)b * T_OUT + T_IN) * (NNODE * CC) + (size_t)n * CC + c;
#pragma unroll
    for (int j = 0; j < JJ; ++j) {
        float s = sBc[j];
#pragma unroll
        for (int t = 0; t < T_IN; ++t) s += a[t] * sWc[j][t];
        float v = (s > 0.f) ? s : 1.6732632423543772f * (__expf(s) - 1.f);
        ob[j * (NNODE * CC)] = 1.0507009873554805f * v;
    }
}

extern "C" void kernel_launch(void* const* d_in, const int* in_sizes, int n_in,
                              void* d_out, int out_size, void* d_ws, size_t ws_size,
                              hipStream_t stream) {
    const float* x        = (const float*)d_in[0];
    const int*   nn       = (const int*)d_in[1];
    const float* agg_w    = (const float*)d_in[2];
    const float* agg_b    = (const float*)d_in[3];
    const float* mh_w     = (const float*)d_in[4];
    const float* mh_b     = (const float*)d_in[5];
    const float* shrink_w = (const float*)d_in[6];
    const float* shrink_b = (const float*)d_in[7];
    float* out = (float*)d_out;

    copy_x_kernel<<<2048, 256, 0, stream>>>((const float4*)x, (float4*)out);
    gal_main<<<(BB * NNODE) / 16, 256, 0, stream>>>(
        x, nn, agg_w, agg_b, mh_w, mh_b, shrink_w, shrink_b, out);
}

// Round 2
// 75.604 us; speedup vs baseline: 1.9043x; 1.9043x over previous
//
#include <hip/hip_runtime.h>

#define BB 4
#define T_IN 12
#define T_OUT 24
#define NNODE 20000
#define CC 16
#define KP1 9
#define NH 8
#define JJ 12                    // T_OUT - T_IN
#define NODES_PER_BLK 64         // 64 nodes x 4 float4-lanes = 256 threads
#define CHUNKS_PER_SLICE 313     // ceil(20000/64)
#define NXCD 8
#define NSLICE (BB * T_IN)       // 48 (b,t) slices
#define SLICES_PER_XCD (NSLICE / NXCD)  // 6

__device__ __forceinline__ float swish1(float s) {
    return s / (1.f + __expf(-0.8f * s));
}

// Phase A: per (b,t) slice — gather 9 neighbors, aggregate, swish.
// Writes a -> out[b, 12+t, :, :] and copies x -> out[b, t, :, :].
// Block -> slice mapping pins each slice to a single XCD (blockIdx % 8),
// processed sequentially, so the 1.28 MB slice stays L2-resident.
__global__ __launch_bounds__(256) void gather_swish(
    const float4* __restrict__ x,    // (B,12,N,16) as float4 rows of 4
    const int* __restrict__ nn,      // (N,9)
    const float* __restrict__ agg_w, // (9,)
    const float* __restrict__ agg_b, // (1,)
    float4* __restrict__ out)        // (B,24,N,16) as float4
{
    const int xcd = blockIdx.x & (NXCD - 1);
    const int j = blockIdx.x >> 3;
    const int slice_local = j / CHUNKS_PER_SLICE;
    const int chunk = j - slice_local * CHUNKS_PER_SLICE;
    const int slice = xcd * SLICES_PER_XCD + slice_local;  // = b*12 + t
    const int b = slice / T_IN;
    const int t = slice - b * T_IN;

    const int tid = threadIdx.x;
    const int r = tid >> 2;            // local node 0..63
    const int q = tid & 3;             // float4 lane (channels 4q..4q+3)
    const int n = chunk * NODES_PER_BLK + r;
    if (n >= NNODE) return;

    // neighbor indices + weights in registers (4 lanes broadcast-share lines)
    int idx[KP1];
    float w[KP1];
#pragma unroll
    for (int k = 0; k < KP1; ++k) {
        idx[k] = nn[n * KP1 + k];
        w[k] = agg_w[k];
        if (idx[k] >= NNODE) { idx[k] = 0; w[k] = 0.f; }  // padded zero-node
    }

    const float4* xs = x + (size_t)slice * (NNODE * 4) + q;  // slice base, lane offset
    const float bias = agg_b[0];
    float4 s; s.x = bias; s.y = bias; s.z = bias; s.w = bias;
#pragma unroll
    for (int k = 0; k < KP1; ++k) {
        float4 v = xs[(size_t)idx[k] * 4];
        s.x += w[k] * v.x; s.y += w[k] * v.y;
        s.z += w[k] * v.z; s.w += w[k] * v.w;
    }
    s.x = swish1(s.x); s.y = swish1(s.y); s.z = swish1(s.z); s.w = swish1(s.w);

    // copy x -> out[:, :12] (slice is L2-hot)
    float4 xv = xs[(size_t)n * 4];
    const size_t out_b = (size_t)b * (T_OUT * NNODE * 4);
    out[out_b + (size_t)t * (NNODE * 4) + n * 4 + q] = xv;
    // stage a -> out[:, 12:]
    out[out_b + (size_t)(T_IN + t) * (NNODE * 4) + n * 4 + q] = s;
}

// Phase B: in-place over out[:, 12:]: EMA over t, collapsed 12x12 matmul, selu.
// Each thread reads its 12 staged float4s into registers then overwrites the
// same 12 addresses — no cross-thread hazard.
__global__ __launch_bounds__(256) void ema_shrink(
    const float* __restrict__ mh_w,      // (8,)
    const float* __restrict__ mh_b,      // (8,)
    const float* __restrict__ shrink_w,  // (12,96)
    const float* __restrict__ shrink_b,  // (12,)
    float4* __restrict__ out)            // (B,24,N,16) as float4
{
    __shared__ float sWc[JJ][T_IN];
    __shared__ float sBc[JJ];
    const int tid = threadIdx.x;

    if (tid < JJ * T_IN) {
        int jo = tid / T_IN, t = tid - jo * T_IN;
        float s = 0.f;
#pragma unroll
        for (int h = 0; h < NH; ++h)
            s += mh_w[h] * shrink_w[jo * (T_IN * NH) + t * NH + h];
        sWc[jo][t] = s;
    }
    if (tid < JJ) {
        float s = shrink_b[tid];
#pragma unroll
        for (int qq = 0; qq < T_IN * NH; ++qq)
            s += mh_b[qq & (NH - 1)] * shrink_w[tid * (T_IN * NH) + qq];
        sBc[tid] = s;
    }
    __syncthreads();

    const int g = blockIdx.x * 256 + tid;      // (b, n*4+q) flat, coalesced
    const int b = g / (NNODE * 4);
    const int rem = g - b * (NNODE * 4);
    const size_t base = ((size_t)b * T_OUT + T_IN) * (NNODE * 4) + rem;

    float4 a[T_IN];
#pragma unroll
    for (int t = 0; t < T_IN; ++t) a[t] = out[base + (size_t)t * (NNODE * 4)];

    // EMA (back-to-front)
#pragma unroll
    for (int t = T_IN - 1; t >= 1; --t) {
        a[t].x = 0.8f * a[t].x + 0.2f * a[t - 1].x;
        a[t].y = 0.8f * a[t].y + 0.2f * a[t - 1].y;
        a[t].z = 0.8f * a[t].z + 0.2f * a[t - 1].z;
        a[t].w = 0.8f * a[t].w + 0.2f * a[t - 1].w;
    }

#pragma unroll
    for (int jo = 0; jo < JJ; ++jo) {
        float4 s;
        s.x = sBc[jo]; s.y = sBc[jo]; s.z = sBc[jo]; s.w = sBc[jo];
#pragma unroll
        for (int t = 0; t < T_IN; ++t) {
            float wv = sWc[jo][t];
            s.x += a[t].x * wv; s.y += a[t].y * wv;
            s.z += a[t].z * wv; s.w += a[t].w * wv;
        }
        s.x = (s.x > 0.f) ? 1.0507009873554805f * s.x
                          : 1.7580993408473766f * (__expf(s.x) - 1.f);
        s.y = (s.y > 0.f) ? 1.0507009873554805f * s.y
                          : 1.7580993408473766f * (__expf(s.y) - 1.f);
        s.z = (s.z > 0.f) ? 1.0507009873554805f * s.z
                          : 1.7580993408473766f * (__expf(s.z) - 1.f);
        s.w = (s.w > 0.f) ? 1.0507009873554805f * s.w
                          : 1.7580993408473766f * (__expf(s.w) - 1.f);
        out[base + (size_t)jo * (NNODE * 4)] = s;
    }
}

extern "C" void kernel_launch(void* const* d_in, const int* in_sizes, int n_in,
                              void* d_out, int out_size, void* d_ws, size_t ws_size,
                              hipStream_t stream) {
    const float* x        = (const float*)d_in[0];
    const int*   nn       = (const int*)d_in[1];
    const float* agg_w    = (const float*)d_in[2];
    const float* agg_b    = (const float*)d_in[3];
    const float* mh_w     = (const float*)d_in[4];
    const float* mh_b     = (const float*)d_in[5];
    const float* shrink_w = (const float*)d_in[6];
    const float* shrink_b = (const float*)d_in[7];
    float4* out = (float4*)d_out;

    gather_swish<<<NXCD * SLICES_PER_XCD * CHUNKS_PER_SLICE, 256, 0, stream>>>(
        (const float4*)x, nn, agg_w, agg_b, out);
    ema_shrink<<<(BB * NNODE * 4) / 256, 256, 0, stream>>>(
        mh_w, mh_b, shrink_w, shrink_b, out);
}